// Round 1
// baseline (1504.114 us; speedup 1.0000x reference)
//
#include <hip/hip_runtime.h>
#include <cstdio>

// ---------------------------------------------------------------------------
// GCN 2-layer forward on MI355X.
// Pipeline:
//   1. cnt[dst]++ histogram (int atomics)
//   2. dinv[i] = rsqrt(cnt[i]+1)            (self-loop included analytically)
//   3. exclusive scan of cnt -> off[]       (3-kernel scan)
//   4. counting-sort edges by dst -> esrc[] (one int atomic per edge)
//   5. h1 = x @ W1                          (fp32 LDS-tiled GEMM, 64x64xBK16)
//   6. agg1: wave-per-node register accumulation + bias + relu -> h1r
//   7. h2 = h1r @ W2
//   8. agg2: + bias -> d_out
// No float atomics anywhere.
// ---------------------------------------------------------------------------

__global__ __launch_bounds__(256) void k_zero(int* p, int n) {
  int i = blockIdx.x * 256 + threadIdx.x;
  if (i < n) p[i] = 0;
}

__global__ __launch_bounds__(256) void k_count(const int* __restrict__ dst,
                                               int* __restrict__ cnt, int e) {
  int i = blockIdx.x * 256 + threadIdx.x;
  if (i < e) atomicAdd(&cnt[dst[i]], 1);
}

__global__ __launch_bounds__(256) void k_dinv(const int* __restrict__ cnt,
                                              float* __restrict__ dinv, int n) {
  int i = blockIdx.x * 256 + threadIdx.x;
  if (i < n) dinv[i] = rsqrtf((float)(cnt[i] + 1));  // +1 = self loop
}

// inclusive scan per 1024-chunk; off[i+1] = within-block inclusive sum
__global__ __launch_bounds__(1024) void k_scan_block(const int* __restrict__ cnt,
                                                     int* __restrict__ off,
                                                     int* __restrict__ bsum, int n) {
  __shared__ int sm[1024];
  int tid = threadIdx.x;
  int i = blockIdx.x * 1024 + tid;
  sm[tid] = (i < n) ? cnt[i] : 0;
  __syncthreads();
  for (int d = 1; d < 1024; d <<= 1) {
    int t = (tid >= d) ? sm[tid - d] : 0;
    __syncthreads();
    sm[tid] += t;
    __syncthreads();
  }
  if (i < n) off[i + 1] = sm[tid];
  if (tid == 1023) bsum[blockIdx.x] = sm[1023];
}

// exclusive scan of block sums (nb <= 1024)
__global__ __launch_bounds__(1024) void k_scan_bsum(int* bsum, int nb) {
  __shared__ int sm[1024];
  int tid = threadIdx.x;
  sm[tid] = (tid < nb) ? bsum[tid] : 0;
  __syncthreads();
  for (int d = 1; d < 1024; d <<= 1) {
    int t = (tid >= d) ? sm[tid - d] : 0;
    __syncthreads();
    sm[tid] += t;
    __syncthreads();
  }
  if (tid < nb) bsum[tid] = (tid > 0) ? sm[tid - 1] : 0;
}

__global__ __launch_bounds__(256) void k_scan_add(int* __restrict__ off,
                                                  const int* __restrict__ bsum, int n) {
  int i = blockIdx.x * 256 + threadIdx.x;
  if (i < n) off[i + 1] += bsum[i >> 10];
  if (i == 0) off[0] = 0;
}

__global__ __launch_bounds__(256) void k_copy(const int* __restrict__ a,
                                              int* __restrict__ b, int n) {
  int i = blockIdx.x * 256 + threadIdx.x;
  if (i < n) b[i] = a[i];
}

__global__ __launch_bounds__(256) void k_scatter(const int* __restrict__ src,
                                                 const int* __restrict__ dst,
                                                 int* __restrict__ cursor,
                                                 int* __restrict__ esrc, int e) {
  int i = blockIdx.x * 256 + threadIdx.x;
  if (i < e) {
    int pos = atomicAdd(&cursor[dst[i]], 1);
    esrc[pos] = src[i];
  }
}

// ---------------------------------------------------------------------------
// fp32 GEMM: C[M,N] = A[M,K] @ B[K,N].  64x64 tile, BK=16, 4x4 micro-tile.
// As stored k-major (transposed) with stride 68 (16B-aligned rows, 2-way max
// bank aliasing which is free on CDNA4).
// ---------------------------------------------------------------------------
__global__ __launch_bounds__(256) void k_gemm(const float* __restrict__ A,
                                              const float* __restrict__ B,
                                              float* __restrict__ C,
                                              int M, int N, int K) {
  __shared__ __align__(16) float As[16][68];
  __shared__ __align__(16) float Bs[16][64];
  const int tid = threadIdx.x;
  const int bm = blockIdx.x * 64;
  const int bn = blockIdx.y * 64;
  const int tx = tid & 15, ty = tid >> 4;

  const int arow = tid >> 2;          // 0..63
  const int akk  = (tid & 3) * 4;     // 0,4,8,12
  const int brow = tid >> 4;          // 0..15
  const int bcol = (tid & 15) * 4;    // 0..60
  const bool avalid = (bm + arow) < M;

  float acc[4][4] = {};

  for (int k0 = 0; k0 < K; k0 += 16) {
    float4 av = make_float4(0.f, 0.f, 0.f, 0.f);
    if (avalid)
      av = *(const float4*)(A + (size_t)(bm + arow) * K + k0 + akk);
    float4 bv = *(const float4*)(B + (size_t)(k0 + brow) * N + bn + bcol);
    __syncthreads();
    As[akk + 0][arow] = av.x;
    As[akk + 1][arow] = av.y;
    As[akk + 2][arow] = av.z;
    As[akk + 3][arow] = av.w;
    *(float4*)&Bs[brow][bcol] = bv;
    __syncthreads();
#pragma unroll
    for (int k = 0; k < 16; ++k) {
      float4 a = *(const float4*)&As[k][ty * 4];
      float4 b = *(const float4*)&Bs[k][tx * 4];
      float ar[4] = {a.x, a.y, a.z, a.w};
      float br[4] = {b.x, b.y, b.z, b.w};
#pragma unroll
      for (int ii = 0; ii < 4; ++ii)
#pragma unroll
        for (int jj = 0; jj < 4; ++jj)
          acc[ii][jj] += ar[ii] * br[jj];
    }
  }

#pragma unroll
  for (int ii = 0; ii < 4; ++ii) {
    int row = bm + ty * 4 + ii;
    if (row < M) {
      float4 v = make_float4(acc[ii][0], acc[ii][1], acc[ii][2], acc[ii][3]);
      *(float4*)&C[(size_t)row * N + bn + tx * 4] = v;
    }
  }
}

// ---------------------------------------------------------------------------
// Aggregation: one wave per destination node. lane holds C/64 channels.
// acc = di * ( di*h[i] + sum_e dinv[src]*h[src] ) + bias  [; relu]
// ---------------------------------------------------------------------------
template <int C, bool RELU>
__global__ __launch_bounds__(256) void k_agg(const float* __restrict__ h,
                                             const int* __restrict__ esrc,
                                             const int* __restrict__ off,
                                             const float* __restrict__ dinv,
                                             const float* __restrict__ bias,
                                             float* __restrict__ out, int n) {
  constexpr int V = C / 64;
  typedef float VecT __attribute__((ext_vector_type(V)));
  int gwave = (blockIdx.x * 256 + threadIdx.x) >> 6;
  int lane = threadIdx.x & 63;
  if (gwave >= n) return;
  const int i = gwave;
  const float di = dinv[i];

  VecT acc = di * (*(const VecT*)(h + (size_t)i * C + lane * V));

  int e = off[i];
  const int e1 = off[i + 1];
  // unroll by 2 for memory-level parallelism
  for (; e + 1 < e1; e += 2) {
    int s0 = esrc[e], s1 = esrc[e + 1];
    float w0 = dinv[s0], w1 = dinv[s1];
    VecT v0 = *(const VecT*)(h + (size_t)s0 * C + lane * V);
    VecT v1 = *(const VecT*)(h + (size_t)s1 * C + lane * V);
    acc += w0 * v0;
    acc += w1 * v1;
  }
  if (e < e1) {
    int s = esrc[e];
    float w = dinv[s];
    acc += w * (*(const VecT*)(h + (size_t)s * C + lane * V));
  }

  VecT bv = *(const VecT*)(bias + lane * V);
  VecT r = acc * di + bv;
  if (RELU) {
#pragma unroll
    for (int v = 0; v < V; ++v) r[v] = fmaxf(r[v], 0.f);
  }
  *(VecT*)(out + (size_t)i * C + lane * V) = r;
}

// ---------------------------------------------------------------------------
extern "C" void kernel_launch(void* const* d_in, const int* in_sizes, int n_in,
                              void* d_out, int out_size, void* d_ws, size_t ws_size,
                              hipStream_t stream) {
  const float* x  = (const float*)d_in[0];
  const int*   ei = (const int*)d_in[1];
  const float* W1 = (const float*)d_in[2];
  const float* b1 = (const float*)d_in[3];
  const float* W2 = (const float*)d_in[4];
  const float* b2 = (const float*)d_in[5];
  float* out = (float*)d_out;

  const int IN_CH = 256, HID = 256, OUT = 128;
  const int N = in_sizes[0] / IN_CH;   // 100000
  const int E = in_sizes[1] / 2;       // 3200000
  const int* src = ei;
  const int* dst = ei + E;

  // workspace layout
  char* p = (char*)d_ws;
  auto alloc = [&](size_t bytes) {
    void* r = (void*)p;
    p += (bytes + 255) & ~(size_t)255;
    return r;
  };
  float* h1   = (float*)alloc((size_t)N * HID * 4);  // reused as h2 later
  float* h1r  = (float*)alloc((size_t)N * HID * 4);
  int*   esrc = (int*)alloc((size_t)E * 4);
  int*   cnt  = (int*)alloc((size_t)N * 4);
  int*   off  = (int*)alloc((size_t)(N + 1) * 4);
  int*   cur  = (int*)alloc((size_t)N * 4);
  float* dinv = (float*)alloc((size_t)N * 4);
  int*   bsum = (int*)alloc(1024 * 4);
  if ((size_t)(p - (char*)d_ws) > ws_size) {
    fprintf(stderr, "kernel_launch: ws too small (need %zu, have %zu)\n",
            (size_t)(p - (char*)d_ws), ws_size);
    return;
  }

  const int nBlkN = (N + 255) / 256;
  const int nBlkE = (E + 255) / 256;
  const int nb = (N + 1023) / 1024;

  // 1. degree histogram
  k_zero<<<nBlkN, 256, 0, stream>>>(cnt, N);
  k_count<<<nBlkE, 256, 0, stream>>>(dst, cnt, E);
  // 2. dinv
  k_dinv<<<nBlkN, 256, 0, stream>>>(cnt, dinv, N);
  // 3. scan -> off
  k_scan_block<<<nb, 1024, 0, stream>>>(cnt, off, bsum, N);
  k_scan_bsum<<<1, 1024, 0, stream>>>(bsum, nb);
  k_scan_add<<<nBlkN, 256, 0, stream>>>(off, bsum, N);
  // 4. counting sort of edges by dst
  k_copy<<<nBlkN, 256, 0, stream>>>(off, cur, N);
  k_scatter<<<nBlkE, 256, 0, stream>>>(src, dst, cur, esrc, E);
  // 5. h1 = x @ W1
  dim3 g1((N + 63) / 64, HID / 64);
  k_gemm<<<g1, 256, 0, stream>>>(x, W1, h1, N, HID, IN_CH);
  // 6. agg layer 1 (+bias, relu)
  int aggBlk = (N + 3) / 4;  // 4 waves per block, wave per node
  k_agg<256, true><<<aggBlk, 256, 0, stream>>>(h1, esrc, off, dinv, b1, h1r, N);
  // 7. h2 = h1r @ W2   (h2 aliases h1 buffer — h1 no longer needed)
  dim3 g2((N + 63) / 64, OUT / 64);
  k_gemm<<<g2, 256, 0, stream>>>(h1r, W2, h1, N, OUT, HID);
  // 8. agg layer 2 (+bias) -> out
  k_agg<128, false><<<aggBlk, 256, 0, stream>>>(h1, esrc, off, dinv, b2, out, N);
}

// Round 2
// 1147.149 us; speedup vs baseline: 1.3112x; 1.3112x over previous
//
#include <hip/hip_runtime.h>
#include <cstdio>

// ---------------------------------------------------------------------------
// GCN 2-layer forward on MI355X.  Round 2: h stored as fp16 (accum fp32).
// Pipeline:
//   1. cnt[dst]++ histogram (int atomics)
//   2. dinv[i] = rsqrt(cnt[i]+1)            (self-loop included analytically)
//   3. exclusive scan of cnt -> off[]       (3-kernel scan)
//   4. counting-sort edges by dst -> esrc[] (one int atomic per edge)
//   5. h1 = fp16(x @ W1)                    (fp32 LDS-tiled GEMM, 64x64xBK16)
//   6. agg1: wave-per-node fp32 register accumulation + bias + relu -> h1r fp16
//   7. h2 = fp16(h1r @ W2)
//   8. agg2: + bias -> d_out fp32
// No float atomics anywhere.
// ---------------------------------------------------------------------------

template <int V> struct vec_t;
template <> struct vec_t<2> {
  typedef float    fv __attribute__((ext_vector_type(2)));
  typedef _Float16 hv __attribute__((ext_vector_type(2)));
};
template <> struct vec_t<4> {
  typedef float    fv __attribute__((ext_vector_type(4)));
  typedef _Float16 hv __attribute__((ext_vector_type(4)));
};

__global__ __launch_bounds__(256) void k_zero(int* p, int n) {
  int i = blockIdx.x * 256 + threadIdx.x;
  if (i < n) p[i] = 0;
}

__global__ __launch_bounds__(256) void k_count(const int* __restrict__ dst,
                                               int* __restrict__ cnt, int e) {
  int i = blockIdx.x * 256 + threadIdx.x;
  if (i < e) atomicAdd(&cnt[dst[i]], 1);
}

__global__ __launch_bounds__(256) void k_dinv(const int* __restrict__ cnt,
                                              float* __restrict__ dinv, int n) {
  int i = blockIdx.x * 256 + threadIdx.x;
  if (i < n) dinv[i] = rsqrtf((float)(cnt[i] + 1));  // +1 = self loop
}

// inclusive scan per 1024-chunk; off[i+1] = within-block inclusive sum
__global__ __launch_bounds__(1024) void k_scan_block(const int* __restrict__ cnt,
                                                     int* __restrict__ off,
                                                     int* __restrict__ bsum, int n) {
  __shared__ int sm[1024];
  int tid = threadIdx.x;
  int i = blockIdx.x * 1024 + tid;
  sm[tid] = (i < n) ? cnt[i] : 0;
  __syncthreads();
  for (int d = 1; d < 1024; d <<= 1) {
    int t = (tid >= d) ? sm[tid - d] : 0;
    __syncthreads();
    sm[tid] += t;
    __syncthreads();
  }
  if (i < n) off[i + 1] = sm[tid];
  if (tid == 1023) bsum[blockIdx.x] = sm[1023];
}

// exclusive scan of block sums (nb <= 1024)
__global__ __launch_bounds__(1024) void k_scan_bsum(int* bsum, int nb) {
  __shared__ int sm[1024];
  int tid = threadIdx.x;
  sm[tid] = (tid < nb) ? bsum[tid] : 0;
  __syncthreads();
  for (int d = 1; d < 1024; d <<= 1) {
    int t = (tid >= d) ? sm[tid - d] : 0;
    __syncthreads();
    sm[tid] += t;
    __syncthreads();
  }
  if (tid < nb) bsum[tid] = (tid > 0) ? sm[tid - 1] : 0;
}

__global__ __launch_bounds__(256) void k_scan_add(int* __restrict__ off,
                                                  const int* __restrict__ bsum, int n) {
  int i = blockIdx.x * 256 + threadIdx.x;
  if (i < n) off[i + 1] += bsum[i >> 10];
  if (i == 0) off[0] = 0;
}

__global__ __launch_bounds__(256) void k_copy(const int* __restrict__ a,
                                              int* __restrict__ b, int n) {
  int i = blockIdx.x * 256 + threadIdx.x;
  if (i < n) b[i] = a[i];
}

__global__ __launch_bounds__(256) void k_scatter(const int* __restrict__ src,
                                                 const int* __restrict__ dst,
                                                 int* __restrict__ cursor,
                                                 int* __restrict__ esrc, int e) {
  int i = blockIdx.x * 256 + threadIdx.x;
  if (i < e) {
    int pos = atomicAdd(&cursor[dst[i]], 1);
    esrc[pos] = src[i];
  }
}

// ---------------------------------------------------------------------------
// fp32 GEMM: C[M,N] = fp16(A[M,K] @ B[K,N]).  A is fp32 or fp16; B fp32;
// C fp16. 64x64 tile, BK=16, 4x4 micro-tile. fp32 accumulate.
// ---------------------------------------------------------------------------
template <typename AT>
__global__ __launch_bounds__(256) void k_gemm(const AT* __restrict__ A,
                                              const float* __restrict__ B,
                                              _Float16* __restrict__ C,
                                              int M, int N, int K) {
  __shared__ __align__(16) float As[16][68];
  __shared__ __align__(16) float Bs[16][64];
  const int tid = threadIdx.x;
  const int bm = blockIdx.x * 64;
  const int bn = blockIdx.y * 64;
  const int tx = tid & 15, ty = tid >> 4;

  const int arow = tid >> 2;          // 0..63
  const int akk  = (tid & 3) * 4;     // 0,4,8,12
  const int brow = tid >> 4;          // 0..15
  const int bcol = (tid & 15) * 4;    // 0..60
  const bool avalid = (bm + arow) < M;

  float acc[4][4] = {};

  for (int k0 = 0; k0 < K; k0 += 16) {
    float4 av = make_float4(0.f, 0.f, 0.f, 0.f);
    if (avalid) {
      const AT* ap = A + (size_t)(bm + arow) * K + k0 + akk;
      if constexpr (sizeof(AT) == 4) {
        av = *(const float4*)ap;
      } else {
        vec_t<4>::hv t = *(const vec_t<4>::hv*)ap;
        av = make_float4((float)t.x, (float)t.y, (float)t.z, (float)t.w);
      }
    }
    float4 bv = *(const float4*)(B + (size_t)(k0 + brow) * N + bn + bcol);
    __syncthreads();
    As[akk + 0][arow] = av.x;
    As[akk + 1][arow] = av.y;
    As[akk + 2][arow] = av.z;
    As[akk + 3][arow] = av.w;
    *(float4*)&Bs[brow][bcol] = bv;
    __syncthreads();
#pragma unroll
    for (int k = 0; k < 16; ++k) {
      float4 a = *(const float4*)&As[k][ty * 4];
      float4 b = *(const float4*)&Bs[k][tx * 4];
      float ar[4] = {a.x, a.y, a.z, a.w};
      float br[4] = {b.x, b.y, b.z, b.w};
#pragma unroll
      for (int ii = 0; ii < 4; ++ii)
#pragma unroll
        for (int jj = 0; jj < 4; ++jj)
          acc[ii][jj] += ar[ii] * br[jj];
    }
  }

#pragma unroll
  for (int ii = 0; ii < 4; ++ii) {
    int row = bm + ty * 4 + ii;
    if (row < M) {
      vec_t<4>::hv v;
      v.x = (_Float16)acc[ii][0];
      v.y = (_Float16)acc[ii][1];
      v.z = (_Float16)acc[ii][2];
      v.w = (_Float16)acc[ii][3];
      *(vec_t<4>::hv*)&C[(size_t)row * N + bn + tx * 4] = v;
    }
  }
}

// ---------------------------------------------------------------------------
// Aggregation: one wave per destination node. lane holds C/64 channels.
// out = di * ( di*h[i] + sum_e dinv[src]*h[src] ) + bias  [; relu]
// h gathered as fp16, accumulated fp32. OutT = _Float16 (layer1) / float.
// ---------------------------------------------------------------------------
template <int C, bool RELU, typename OutT>
__global__ __launch_bounds__(256) void k_agg(const _Float16* __restrict__ h,
                                             const int* __restrict__ esrc,
                                             const int* __restrict__ off,
                                             const float* __restrict__ dinv,
                                             const float* __restrict__ bias,
                                             OutT* __restrict__ out, int n) {
  constexpr int V = C / 64;
  typedef typename vec_t<V>::fv FV;
  typedef typename vec_t<V>::hv HV;
  int gwave = (blockIdx.x * 256 + threadIdx.x) >> 6;
  int lane = threadIdx.x & 63;
  if (gwave >= n) return;
  const int i = gwave;
  const float di = dinv[i];

  FV acc = di * __builtin_convertvector(
                    *(const HV*)(h + (size_t)i * C + lane * V), FV);

  int e = off[i];
  const int e1 = off[i + 1];
  for (; e + 3 < e1; e += 4) {
    int s0 = esrc[e], s1 = esrc[e + 1], s2 = esrc[e + 2], s3 = esrc[e + 3];
    float w0 = dinv[s0], w1 = dinv[s1], w2 = dinv[s2], w3 = dinv[s3];
    HV v0 = *(const HV*)(h + (size_t)s0 * C + lane * V);
    HV v1 = *(const HV*)(h + (size_t)s1 * C + lane * V);
    HV v2 = *(const HV*)(h + (size_t)s2 * C + lane * V);
    HV v3 = *(const HV*)(h + (size_t)s3 * C + lane * V);
    acc += w0 * __builtin_convertvector(v0, FV);
    acc += w1 * __builtin_convertvector(v1, FV);
    acc += w2 * __builtin_convertvector(v2, FV);
    acc += w3 * __builtin_convertvector(v3, FV);
  }
  for (; e < e1; ++e) {
    int s = esrc[e];
    acc += dinv[s] * __builtin_convertvector(
                         *(const HV*)(h + (size_t)s * C + lane * V), FV);
  }

  FV bv = *(const FV*)(bias + lane * V);
  FV r = acc * di + bv;
  if (RELU) {
#pragma unroll
    for (int v = 0; v < V; ++v) r[v] = fmaxf(r[v], 0.f);
  }
  if constexpr (sizeof(OutT) == 2) {
    *(HV*)(out + (size_t)i * C + lane * V) = __builtin_convertvector(r, HV);
  } else {
    *(FV*)(out + (size_t)i * C + lane * V) = r;
  }
}

// ---------------------------------------------------------------------------
extern "C" void kernel_launch(void* const* d_in, const int* in_sizes, int n_in,
                              void* d_out, int out_size, void* d_ws, size_t ws_size,
                              hipStream_t stream) {
  const float* x  = (const float*)d_in[0];
  const int*   ei = (const int*)d_in[1];
  const float* W1 = (const float*)d_in[2];
  const float* b1 = (const float*)d_in[3];
  const float* W2 = (const float*)d_in[4];
  const float* b2 = (const float*)d_in[5];
  float* out = (float*)d_out;

  const int IN_CH = 256, HID = 256, OUT = 128;
  const int N = in_sizes[0] / IN_CH;   // 100000
  const int E = in_sizes[1] / 2;       // 3200000
  const int* src = ei;
  const int* dst = ei + E;

  // workspace layout
  char* p = (char*)d_ws;
  auto alloc = [&](size_t bytes) {
    void* r = (void*)p;
    p += (bytes + 255) & ~(size_t)255;
    return r;
  };
  _Float16* h1   = (_Float16*)alloc((size_t)N * HID * 2);  // reused as h2 later
  _Float16* h1r  = (_Float16*)alloc((size_t)N * HID * 2);
  int*      esrc = (int*)alloc((size_t)E * 4);
  int*      cnt  = (int*)alloc((size_t)N * 4);
  int*      off  = (int*)alloc((size_t)(N + 1) * 4);
  int*      cur  = (int*)alloc((size_t)N * 4);
  float*    dinv = (float*)alloc((size_t)N * 4);
  int*      bsum = (int*)alloc(1024 * 4);
  if ((size_t)(p - (char*)d_ws) > ws_size) {
    fprintf(stderr, "kernel_launch: ws too small (need %zu, have %zu)\n",
            (size_t)(p - (char*)d_ws), ws_size);
    return;
  }

  const int nBlkN = (N + 255) / 256;
  const int nBlkE = (E + 255) / 256;
  const int nb = (N + 1023) / 1024;

  // 1. degree histogram
  k_zero<<<nBlkN, 256, 0, stream>>>(cnt, N);
  k_count<<<nBlkE, 256, 0, stream>>>(dst, cnt, E);
  // 2. dinv
  k_dinv<<<nBlkN, 256, 0, stream>>>(cnt, dinv, N);
  // 3. scan -> off
  k_scan_block<<<nb, 1024, 0, stream>>>(cnt, off, bsum, N);
  k_scan_bsum<<<1, 1024, 0, stream>>>(bsum, nb);
  k_scan_add<<<nBlkN, 256, 0, stream>>>(off, bsum, N);
  // 4. counting sort of edges by dst
  k_copy<<<nBlkN, 256, 0, stream>>>(off, cur, N);
  k_scatter<<<nBlkE, 256, 0, stream>>>(src, dst, cur, esrc, E);
  // 5. h1 = fp16(x @ W1)
  dim3 g1((N + 63) / 64, HID / 64);
  k_gemm<float><<<g1, 256, 0, stream>>>(x, W1, h1, N, HID, IN_CH);
  // 6. agg layer 1 (+bias, relu) -> h1r fp16
  int aggBlk = (N + 3) / 4;  // 4 waves per block, wave per node
  k_agg<256, true, _Float16><<<aggBlk, 256, 0, stream>>>(h1, esrc, off, dinv, b1, h1r, N);
  // 7. h2 = fp16(h1r @ W2)   (h2 aliases h1 buffer — h1 no longer needed)
  dim3 g2((N + 63) / 64, OUT / 64);
  k_gemm<_Float16><<<g2, 256, 0, stream>>>(h1r, W2, h1, N, OUT, HID);
  // 8. agg layer 2 (+bias) -> out fp32
  k_agg<128, false, float><<<aggBlk, 256, 0, stream>>>(h1, esrc, off, dinv, b2, out, N);
}

// Round 3
// 883.850 us; speedup vs baseline: 1.7018x; 1.2979x over previous
//
#include <hip/hip_runtime.h>
#include <cstdio>

// ---------------------------------------------------------------------------
// GCN 2-layer forward on MI355X.  Round 3: bucketed counting sort (write
// locality), fp16 h storage, fp32 accumulation everywhere.
// Pipeline:
//   1. k_bhist:    bucket histogram of dst>>8  (LDS-privatized)
//   2. k_bscan:    scan 391 buckets -> bbase[], init gcur[]
//   3. k_partition: edges -> tmp[] packed (src,dst), bucket-partitioned,
//                   contiguous runs per (block,bucket)  [low write amp]
//   4. k_bucket:   per-bucket LDS sort -> esrc[], off[], dinv[]
//   5. h1 = fp16(x @ W1)          (fp32 LDS-tiled GEMM 64x64xBK16)
//   6. agg1 (wave/node, fp32 acc) + bias + relu -> h1r fp16
//   7. h2 = fp16(h1r @ W2)
//   8. agg2 + bias -> d_out fp32
// ---------------------------------------------------------------------------

#define NPB 256        // nodes per bucket (power of 2: bucket = dst >> 8)
#define PCHUNK 8192    // edges per partition block

template <int V> struct vec_t;
template <> struct vec_t<2> {
  typedef float    fv __attribute__((ext_vector_type(2)));
  typedef _Float16 hv __attribute__((ext_vector_type(2)));
};
template <> struct vec_t<4> {
  typedef float    fv __attribute__((ext_vector_type(4)));
  typedef _Float16 hv __attribute__((ext_vector_type(4)));
};

__global__ __launch_bounds__(256) void k_zero(int* p, int n) {
  int i = blockIdx.x * 256 + threadIdx.x;
  if (i < n) p[i] = 0;
}

// 1. bucket histogram, LDS-privatized
__global__ __launch_bounds__(256) void k_bhist(const int* __restrict__ dst,
                                               int* __restrict__ bcnt,
                                               int e, int nb) {
  __shared__ int h[512];
  for (int i = threadIdx.x; i < nb; i += 256) h[i] = 0;
  __syncthreads();
  int c0 = blockIdx.x * PCHUNK;
  int c1 = min(c0 + PCHUNK, e);
  for (int i = c0 + threadIdx.x; i < c1; i += 256)
    atomicAdd(&h[dst[i] >> 8], 1);
  __syncthreads();
  for (int i = threadIdx.x; i < nb; i += 256)
    if (h[i]) atomicAdd(&bcnt[i], h[i]);
}

// 2. single-block scan of bucket counts -> bbase[0..nb], gcur init
__global__ __launch_bounds__(512) void k_bscan(const int* __restrict__ bcnt,
                                               int* __restrict__ bbase,
                                               int* __restrict__ gcur, int nb) {
  __shared__ int sm[512];
  int tid = threadIdx.x;
  sm[tid] = (tid < nb) ? bcnt[tid] : 0;
  __syncthreads();
  for (int d = 1; d < 512; d <<= 1) {
    int t = (tid >= d) ? sm[tid - d] : 0;
    __syncthreads();
    sm[tid] += t;
    __syncthreads();
  }
  int ex = (tid == 0) ? 0 : sm[tid - 1];
  if (tid < nb) {
    bbase[tid] = ex;
    gcur[tid] = ex;
  }
  if (tid == nb) bbase[nb] = sm[nb - 1];
}

// 3. bucket partition: contiguous runs of packed (src,dst) per (block,bucket)
__global__ __launch_bounds__(256) void k_partition(const int* __restrict__ src,
                                                   const int* __restrict__ dst,
                                                   int* __restrict__ gcur,
                                                   uint2* __restrict__ tmp,
                                                   int e, int nb) {
  __shared__ int hist[512];
  __shared__ int base[512];
  for (int i = threadIdx.x; i < nb; i += 256) hist[i] = 0;
  __syncthreads();
  int c0 = blockIdx.x * PCHUNK;
  int c1 = min(c0 + PCHUNK, e);
  for (int i = c0 + threadIdx.x; i < c1; i += 256)
    atomicAdd(&hist[dst[i] >> 8], 1);
  __syncthreads();
  for (int i = threadIdx.x; i < nb; i += 256) {
    int c = hist[i];
    base[i] = c ? atomicAdd(&gcur[i], c) : 0;
    hist[i] = 0;  // reuse as local cursor
  }
  __syncthreads();
  for (int i = c0 + threadIdx.x; i < c1; i += 256) {
    int d = dst[i];
    int b = d >> 8;
    int pos = base[b] + atomicAdd(&hist[b], 1);
    uint2 v;
    v.x = (unsigned)src[i];
    v.y = (unsigned)d;
    tmp[pos] = v;
  }
}

// 4. per-bucket sort: produce esrc (sorted by dst), off[], dinv[]
__global__ __launch_bounds__(256) void k_bucket(const uint2* __restrict__ tmp,
                                                const int* __restrict__ bbase,
                                                int* __restrict__ off,
                                                float* __restrict__ dinv,
                                                int* __restrict__ esrc, int n) {
  __shared__ int lcnt[NPB];
  __shared__ int lsum[NPB];
  __shared__ int lcur[NPB];
  const int b = blockIdx.x;
  const int tid = threadIdx.x;
  const int r0 = b << 8;
  const int nn = min(NPB, n - r0);
  const int lo = bbase[b], hi = bbase[b + 1];

  lcnt[tid] = 0;
  __syncthreads();
  for (int i = lo + tid; i < hi; i += 256)
    atomicAdd(&lcnt[tmp[i].y & (NPB - 1)], 1);
  __syncthreads();
  // inclusive scan of lcnt
  lsum[tid] = lcnt[tid];
  __syncthreads();
  for (int d = 1; d < NPB; d <<= 1) {
    int t = (tid >= d) ? lsum[tid - d] : 0;
    __syncthreads();
    lsum[tid] += t;
    __syncthreads();
  }
  int ex = (tid == 0) ? 0 : lsum[tid - 1];
  if (tid < nn) {
    off[r0 + tid] = lo + ex;
    dinv[r0 + tid] = rsqrtf((float)(lcnt[tid] + 1));  // +1 self loop
    lcur[tid] = lo + ex;
  }
  if (r0 + nn == n && tid == 0) off[n] = hi;
  __syncthreads();
  for (int i = lo + tid; i < hi; i += 256) {
    uint2 t2 = tmp[i];
    int pos = atomicAdd(&lcur[t2.y & (NPB - 1)], 1);
    esrc[pos] = (int)t2.x;
  }
}

// ---------------------------------------------------------------------------
// fp32 GEMM: C[M,N] = fp16(A[M,K] @ B[K,N]).  A fp32 or fp16; B fp32;
// C fp16. 64x64 tile, BK=16, 4x4 micro-tile. fp32 accumulate.
// ---------------------------------------------------------------------------
template <typename AT>
__global__ __launch_bounds__(256) void k_gemm(const AT* __restrict__ A,
                                              const float* __restrict__ B,
                                              _Float16* __restrict__ C,
                                              int M, int N, int K) {
  __shared__ __align__(16) float As[16][68];
  __shared__ __align__(16) float Bs[16][64];
  const int tid = threadIdx.x;
  const int bm = blockIdx.x * 64;
  const int bn = blockIdx.y * 64;
  const int tx = tid & 15, ty = tid >> 4;

  const int arow = tid >> 2;          // 0..63
  const int akk  = (tid & 3) * 4;     // 0,4,8,12
  const int brow = tid >> 4;          // 0..15
  const int bcol = (tid & 15) * 4;    // 0..60
  const bool avalid = (bm + arow) < M;

  float acc[4][4] = {};

  for (int k0 = 0; k0 < K; k0 += 16) {
    float4 av = make_float4(0.f, 0.f, 0.f, 0.f);
    if (avalid) {
      const AT* ap = A + (size_t)(bm + arow) * K + k0 + akk;
      if constexpr (sizeof(AT) == 4) {
        av = *(const float4*)ap;
      } else {
        vec_t<4>::hv t = *(const vec_t<4>::hv*)ap;
        av = make_float4((float)t.x, (float)t.y, (float)t.z, (float)t.w);
      }
    }
    float4 bv = *(const float4*)(B + (size_t)(k0 + brow) * N + bn + bcol);
    __syncthreads();
    As[akk + 0][arow] = av.x;
    As[akk + 1][arow] = av.y;
    As[akk + 2][arow] = av.z;
    As[akk + 3][arow] = av.w;
    *(float4*)&Bs[brow][bcol] = bv;
    __syncthreads();
#pragma unroll
    for (int k = 0; k < 16; ++k) {
      float4 a = *(const float4*)&As[k][ty * 4];
      float4 b = *(const float4*)&Bs[k][tx * 4];
      float ar[4] = {a.x, a.y, a.z, a.w};
      float br[4] = {b.x, b.y, b.z, b.w};
#pragma unroll
      for (int ii = 0; ii < 4; ++ii)
#pragma unroll
        for (int jj = 0; jj < 4; ++jj)
          acc[ii][jj] += ar[ii] * br[jj];
    }
  }

#pragma unroll
  for (int ii = 0; ii < 4; ++ii) {
    int row = bm + ty * 4 + ii;
    if (row < M) {
      vec_t<4>::hv v;
      v.x = (_Float16)acc[ii][0];
      v.y = (_Float16)acc[ii][1];
      v.z = (_Float16)acc[ii][2];
      v.w = (_Float16)acc[ii][3];
      *(vec_t<4>::hv*)&C[(size_t)row * N + bn + tx * 4] = v;
    }
  }
}

// ---------------------------------------------------------------------------
// Aggregation: one wave per destination node. lane holds C/64 channels.
// out = di * ( di*h[i] + sum_e dinv[src]*h[src] ) + bias  [; relu]
// h gathered as fp16, accumulated fp32. OutT = _Float16 (layer1) / float.
// ---------------------------------------------------------------------------
template <int C, bool RELU, typename OutT>
__global__ __launch_bounds__(256) void k_agg(const _Float16* __restrict__ h,
                                             const int* __restrict__ esrc,
                                             const int* __restrict__ off,
                                             const float* __restrict__ dinv,
                                             const float* __restrict__ bias,
                                             OutT* __restrict__ out, int n) {
  constexpr int V = C / 64;
  typedef typename vec_t<V>::fv FV;
  typedef typename vec_t<V>::hv HV;
  int gwave = (blockIdx.x * 256 + threadIdx.x) >> 6;
  int lane = threadIdx.x & 63;
  if (gwave >= n) return;
  const int i = gwave;
  const float di = dinv[i];

  FV acc = di * __builtin_convertvector(
                    *(const HV*)(h + (size_t)i * C + lane * V), FV);

  int e = off[i];
  const int e1 = off[i + 1];
  for (; e + 3 < e1; e += 4) {
    int s0 = esrc[e], s1 = esrc[e + 1], s2 = esrc[e + 2], s3 = esrc[e + 3];
    float w0 = dinv[s0], w1 = dinv[s1], w2 = dinv[s2], w3 = dinv[s3];
    HV v0 = *(const HV*)(h + (size_t)s0 * C + lane * V);
    HV v1 = *(const HV*)(h + (size_t)s1 * C + lane * V);
    HV v2 = *(const HV*)(h + (size_t)s2 * C + lane * V);
    HV v3 = *(const HV*)(h + (size_t)s3 * C + lane * V);
    acc += w0 * __builtin_convertvector(v0, FV);
    acc += w1 * __builtin_convertvector(v1, FV);
    acc += w2 * __builtin_convertvector(v2, FV);
    acc += w3 * __builtin_convertvector(v3, FV);
  }
  for (; e < e1; ++e) {
    int s = esrc[e];
    acc += dinv[s] * __builtin_convertvector(
                         *(const HV*)(h + (size_t)s * C + lane * V), FV);
  }

  FV bv = *(const FV*)(bias + lane * V);
  FV r = acc * di + bv;
  if (RELU) {
#pragma unroll
    for (int v = 0; v < V; ++v) r[v] = fmaxf(r[v], 0.f);
  }
  if constexpr (sizeof(OutT) == 2) {
    *(HV*)(out + (size_t)i * C + lane * V) = __builtin_convertvector(r, HV);
  } else {
    *(FV*)(out + (size_t)i * C + lane * V) = r;
  }
}

// ---------------------------------------------------------------------------
extern "C" void kernel_launch(void* const* d_in, const int* in_sizes, int n_in,
                              void* d_out, int out_size, void* d_ws, size_t ws_size,
                              hipStream_t stream) {
  const float* x  = (const float*)d_in[0];
  const int*   ei = (const int*)d_in[1];
  const float* W1 = (const float*)d_in[2];
  const float* b1 = (const float*)d_in[3];
  const float* W2 = (const float*)d_in[4];
  const float* b2 = (const float*)d_in[5];
  float* out = (float*)d_out;

  const int IN_CH = 256, HID = 256, OUT = 128;
  const int N = in_sizes[0] / IN_CH;   // 100000
  const int E = in_sizes[1] / 2;       // 3200000
  const int* src = ei;
  const int* dst = ei + E;
  const int NB = (N + NPB - 1) / NPB;  // 391 buckets

  // workspace layout
  char* p = (char*)d_ws;
  auto alloc = [&](size_t bytes) {
    void* r = (void*)p;
    p += (bytes + 255) & ~(size_t)255;
    return r;
  };
  _Float16* h1   = (_Float16*)alloc((size_t)N * HID * 2);  // reused as h2
  _Float16* h1r  = (_Float16*)alloc((size_t)N * HID * 2);
  int*      esrc = (int*)alloc((size_t)E * 4);
  uint2*    tmp  = (uint2*)alloc((size_t)E * 8);
  int*      off  = (int*)alloc((size_t)(N + 1) * 4);
  float*    dinv = (float*)alloc((size_t)N * 4);
  int*      bcnt = (int*)alloc((size_t)(NB + 1) * 4);
  int*      bbase= (int*)alloc((size_t)(NB + 1) * 4);
  int*      gcur = (int*)alloc((size_t)(NB + 1) * 4);
  if ((size_t)(p - (char*)d_ws) > ws_size) {
    fprintf(stderr, "kernel_launch: ws too small (need %zu, have %zu)\n",
            (size_t)(p - (char*)d_ws), ws_size);
    return;
  }

  const int nBlkP = (E + PCHUNK - 1) / PCHUNK;  // 391

  // 1-2. bucket histogram + scan
  k_zero<<<(NB + 255) / 256, 256, 0, stream>>>(bcnt, NB);
  k_bhist<<<nBlkP, 256, 0, stream>>>(dst, bcnt, E, NB);
  k_bscan<<<1, 512, 0, stream>>>(bcnt, bbase, gcur, NB);
  // 3. partition into buckets
  k_partition<<<nBlkP, 256, 0, stream>>>(src, dst, gcur, tmp, E, NB);
  // 4. per-bucket sort -> esrc, off, dinv
  k_bucket<<<NB, 256, 0, stream>>>(tmp, bbase, off, dinv, esrc, N);
  // 5. h1 = fp16(x @ W1)
  dim3 g1((N + 63) / 64, HID / 64);
  k_gemm<float><<<g1, 256, 0, stream>>>(x, W1, h1, N, HID, IN_CH);
  // 6. agg layer 1 (+bias, relu) -> h1r fp16
  int aggBlk = (N + 3) / 4;  // 4 waves per block, wave per node
  k_agg<256, true, _Float16><<<aggBlk, 256, 0, stream>>>(h1, esrc, off, dinv, b1, h1r, N);
  // 7. h2 = fp16(h1r @ W2)   (aliases h1 buffer)
  dim3 g2((N + 63) / 64, OUT / 64);
  k_gemm<_Float16><<<g2, 256, 0, stream>>>(h1r, W2, h1, N, OUT, HID);
  // 8. agg layer 2 (+bias) -> out fp32
  k_agg<128, false, float><<<aggBlk, 256, 0, stream>>>(h1, esrc, off, dinv, b2, out, N);
}

// Round 4
// 746.869 us; speedup vs baseline: 2.0139x; 1.1834x over previous
//
#include <hip/hip_runtime.h>
#include <cstdio>

// ---------------------------------------------------------------------------
// GCN 2-layer forward on MI355X.  Round 4: MFMA split-fp16 GEMMs.
// Pipeline:
//   1. k_bhist:     bucket histogram of dst>>8  (LDS-privatized)
//   2. k_bscan:     scan 391 buckets -> bbase[], init gcur[]
//   3. k_partition: edges -> tmp[] packed (src,dst), bucket-partitioned
//   4. k_bucket:    per-bucket LDS sort -> esrc[], off[], dinv[]
//   5. k_castWT:    W -> (Wh,Wl) fp16 split, TRANSPOSED [N][K]
//   6. k_gemm_mfma<float,3>:  h1 = fp16(x @ W1)  via Ah*Bh+Ah*Bl+Al*Bh
//   7. agg1 (wave/node, fp32 acc) + bias + relu -> h1r fp16
//   8. k_gemm_mfma<half,2>:   h2 = fp16(h1r @ W2) via A*Bh+A*Bl
//   9. agg2 + bias -> d_out fp32
// Split-fp16 MFMA: residual error ~4e-6 (fp32-equivalent); h stored fp16.
// ---------------------------------------------------------------------------

#define NPB 256        // nodes per bucket (power of 2: bucket = dst >> 8)
#define PCHUNK 8192    // edges per partition block

template <int V> struct vec_t;
template <> struct vec_t<2> {
  typedef float    fv __attribute__((ext_vector_type(2)));
  typedef _Float16 hv __attribute__((ext_vector_type(2)));
};
template <> struct vec_t<4> {
  typedef float    fv __attribute__((ext_vector_type(4)));
  typedef _Float16 hv __attribute__((ext_vector_type(4)));
};
typedef _Float16 half4v __attribute__((ext_vector_type(4)));
typedef _Float16 half8v __attribute__((ext_vector_type(8)));
typedef float    f32x4  __attribute__((ext_vector_type(4)));

__global__ __launch_bounds__(256) void k_zero(int* p, int n) {
  int i = blockIdx.x * 256 + threadIdx.x;
  if (i < n) p[i] = 0;
}

// 1. bucket histogram, LDS-privatized
__global__ __launch_bounds__(256) void k_bhist(const int* __restrict__ dst,
                                               int* __restrict__ bcnt,
                                               int e, int nb) {
  __shared__ int h[512];
  for (int i = threadIdx.x; i < nb; i += 256) h[i] = 0;
  __syncthreads();
  int c0 = blockIdx.x * PCHUNK;
  int c1 = min(c0 + PCHUNK, e);
  for (int i = c0 + threadIdx.x; i < c1; i += 256)
    atomicAdd(&h[dst[i] >> 8], 1);
  __syncthreads();
  for (int i = threadIdx.x; i < nb; i += 256)
    if (h[i]) atomicAdd(&bcnt[i], h[i]);
}

// 2. single-block scan of bucket counts -> bbase[0..nb], gcur init
__global__ __launch_bounds__(512) void k_bscan(const int* __restrict__ bcnt,
                                               int* __restrict__ bbase,
                                               int* __restrict__ gcur, int nb) {
  __shared__ int sm[512];
  int tid = threadIdx.x;
  sm[tid] = (tid < nb) ? bcnt[tid] : 0;
  __syncthreads();
  for (int d = 1; d < 512; d <<= 1) {
    int t = (tid >= d) ? sm[tid - d] : 0;
    __syncthreads();
    sm[tid] += t;
    __syncthreads();
  }
  int ex = (tid == 0) ? 0 : sm[tid - 1];
  if (tid < nb) {
    bbase[tid] = ex;
    gcur[tid] = ex;
  }
  if (tid == nb) bbase[nb] = sm[nb - 1];
}

// 3. bucket partition: contiguous runs of packed (src,dst) per (block,bucket)
__global__ __launch_bounds__(256) void k_partition(const int* __restrict__ src,
                                                   const int* __restrict__ dst,
                                                   int* __restrict__ gcur,
                                                   uint2* __restrict__ tmp,
                                                   int e, int nb) {
  __shared__ int hist[512];
  __shared__ int base[512];
  for (int i = threadIdx.x; i < nb; i += 256) hist[i] = 0;
  __syncthreads();
  int c0 = blockIdx.x * PCHUNK;
  int c1 = min(c0 + PCHUNK, e);
  for (int i = c0 + threadIdx.x; i < c1; i += 256)
    atomicAdd(&hist[dst[i] >> 8], 1);
  __syncthreads();
  for (int i = threadIdx.x; i < nb; i += 256) {
    int c = hist[i];
    base[i] = c ? atomicAdd(&gcur[i], c) : 0;
    hist[i] = 0;  // reuse as local cursor
  }
  __syncthreads();
  for (int i = c0 + threadIdx.x; i < c1; i += 256) {
    int d = dst[i];
    int b = d >> 8;
    int pos = base[b] + atomicAdd(&hist[b], 1);
    uint2 v;
    v.x = (unsigned)src[i];
    v.y = (unsigned)d;
    tmp[pos] = v;
  }
}

// 4. per-bucket sort: produce esrc (sorted by dst), off[], dinv[]
__global__ __launch_bounds__(256) void k_bucket(const uint2* __restrict__ tmp,
                                                const int* __restrict__ bbase,
                                                int* __restrict__ off,
                                                float* __restrict__ dinv,
                                                int* __restrict__ esrc, int n) {
  __shared__ int lcnt[NPB];
  __shared__ int lsum[NPB];
  __shared__ int lcur[NPB];
  const int b = blockIdx.x;
  const int tid = threadIdx.x;
  const int r0 = b << 8;
  const int nn = min(NPB, n - r0);
  const int lo = bbase[b], hi = bbase[b + 1];

  lcnt[tid] = 0;
  __syncthreads();
  for (int i = lo + tid; i < hi; i += 256)
    atomicAdd(&lcnt[tmp[i].y & (NPB - 1)], 1);
  __syncthreads();
  lsum[tid] = lcnt[tid];
  __syncthreads();
  for (int d = 1; d < NPB; d <<= 1) {
    int t = (tid >= d) ? lsum[tid - d] : 0;
    __syncthreads();
    lsum[tid] += t;
    __syncthreads();
  }
  int ex = (tid == 0) ? 0 : lsum[tid - 1];
  if (tid < nn) {
    off[r0 + tid] = lo + ex;
    dinv[r0 + tid] = rsqrtf((float)(lcnt[tid] + 1));  // +1 self loop
    lcur[tid] = lo + ex;
  }
  if (r0 + nn == n && tid == 0) off[n] = hi;
  __syncthreads();
  for (int i = lo + tid; i < hi; i += 256) {
    uint2 t2 = tmp[i];
    int pos = atomicAdd(&lcur[t2.y & (NPB - 1)], 1);
    esrc[pos] = (int)t2.x;
  }
}

// ---------------------------------------------------------------------------
// 5. W -> split fp16, transposed: WhT/WlT are [N][K] so the GEMM B-fragment
// (8 consecutive k at fixed n) is one contiguous 16 B load.
// ---------------------------------------------------------------------------
__global__ __launch_bounds__(256) void k_castWT(const float* __restrict__ W,
                                                _Float16* __restrict__ WhT,
                                                _Float16* __restrict__ WlT,
                                                int K, int N) {
  int i = blockIdx.x * 256 + threadIdx.x;
  if (i >= K * N) return;
  int n = i % N, k = i / N;      // coalesced read of W[k][n]
  float v = W[i];
  _Float16 h = (_Float16)v;
  WhT[(size_t)n * K + k] = h;
  WlT[(size_t)n * K + k] = (_Float16)(v - (float)h);
}

// ---------------------------------------------------------------------------
// 6/8. MFMA GEMM: C[M,N] = fp16(A[M,K] @ B[K,N]), fp32 accumulate.
// NTERMS=3 (AT=float):    acc += Ah*Bh + Ah*Bl + Al*Bh   (fp32-exact)
// NTERMS=2 (AT=_Float16): acc += A*Bh + A*Bl
// Tile: 128x128, BK=32, 4 waves, each wave 64x64 = 4x4 frags of 16x16x32.
// A staged in LDS (stride 40 halves -> <=2-way bank aliasing on b128 reads);
// B frags loaded directly from global WhT/WlT [N][K] (L2-resident).
// MFMA layouts (guide §3, m89/m91-verified): A[m=lane&15][k=quad*8+j],
// B[k=quad*8+j][n=lane&15], C/D col=lane&15 row=quad*4+reg.
// ---------------------------------------------------------------------------
template <typename AT, int NTERMS>
__global__ __launch_bounds__(256, 2) void k_gemm_mfma(
    const AT* __restrict__ A, const _Float16* __restrict__ BhT,
    const _Float16* __restrict__ BlT, _Float16* __restrict__ C,
    int M, int N, int K) {
  constexpr bool SPLITA = (NTERMS == 3);
  __shared__ _Float16 Ah[128][40];
  __shared__ _Float16 Al[SPLITA ? 128 : 1][40];

  const int tid = threadIdx.x;
  const int bm = blockIdx.x * 128;
  const int bn = blockIdx.y * 128;

  // staging map: thread -> (row, 16-wide k segment)
  const int arow = tid >> 1;
  const int acol = (tid & 1) * 16;
  const bool avalid = (bm + arow) < M;
  const AT* aptr = A + (size_t)(bm + arow) * K + acol;

  // wave decomposition
  const int wave = tid >> 6, lane = tid & 63;
  const int wm = (wave & 1) * 64, wn = (wave >> 1) * 64;
  const int lr = lane & 15, quad = lane >> 4;

  const _Float16* bh0 = BhT + (size_t)(bn + wn + lr) * K + quad * 8;
  const _Float16* bl0 = BlT + (size_t)(bn + wn + lr) * K + quad * 8;

  f32x4 acc[4][4] = {};

  for (int k0 = 0; k0 < K; k0 += 32) {
    __syncthreads();
    if (avalid) {
#pragma unroll
      for (int ii = 0; ii < 4; ++ii) {
        if constexpr (SPLITA) {
          f32x4 v = *(const f32x4*)(aptr + k0 + ii * 4);
          half4v hv, lv;
#pragma unroll
          for (int j = 0; j < 4; ++j) {
            hv[j] = (_Float16)v[j];
            lv[j] = (_Float16)(v[j] - (float)hv[j]);
          }
          *(half4v*)&Ah[arow][acol + ii * 4] = hv;
          *(half4v*)&Al[arow][acol + ii * 4] = lv;
        } else {
          half4v v = *(const half4v*)(aptr + k0 + ii * 4);
          *(half4v*)&Ah[arow][acol + ii * 4] = v;
        }
      }
    } else {
      half4v z = {};
#pragma unroll
      for (int ii = 0; ii < 4; ++ii) {
        *(half4v*)&Ah[arow][acol + ii * 4] = z;
        if constexpr (SPLITA) *(half4v*)&Al[arow][acol + ii * 4] = z;
      }
    }
    __syncthreads();

    half8v af[4], alf[4], bhf[4], blf[4];
#pragma unroll
    for (int mi = 0; mi < 4; ++mi) {
      af[mi] = *(const half8v*)&Ah[wm + mi * 16 + lr][quad * 8];
      if constexpr (SPLITA)
        alf[mi] = *(const half8v*)&Al[wm + mi * 16 + lr][quad * 8];
    }
#pragma unroll
    for (int ni = 0; ni < 4; ++ni) {
      bhf[ni] = *(const half8v*)(bh0 + (size_t)(ni * 16) * K + k0);
      blf[ni] = *(const half8v*)(bl0 + (size_t)(ni * 16) * K + k0);
    }
#pragma unroll
    for (int mi = 0; mi < 4; ++mi)
#pragma unroll
      for (int ni = 0; ni < 4; ++ni) {
        acc[mi][ni] = __builtin_amdgcn_mfma_f32_16x16x32_f16(
            af[mi], bhf[ni], acc[mi][ni], 0, 0, 0);
        acc[mi][ni] = __builtin_amdgcn_mfma_f32_16x16x32_f16(
            af[mi], blf[ni], acc[mi][ni], 0, 0, 0);
        if constexpr (SPLITA)
          acc[mi][ni] = __builtin_amdgcn_mfma_f32_16x16x32_f16(
              alf[mi], bhf[ni], acc[mi][ni], 0, 0, 0);
      }
  }

  // epilogue: C/D frag col=lane&15, row=quad*4+r
#pragma unroll
  for (int mi = 0; mi < 4; ++mi)
#pragma unroll
    for (int r = 0; r < 4; ++r) {
      int row = bm + wm + mi * 16 + quad * 4 + r;
      if (row < M) {
#pragma unroll
        for (int ni = 0; ni < 4; ++ni)
          C[(size_t)row * N + bn + wn + ni * 16 + lr] =
              (_Float16)acc[mi][ni][r];
      }
    }
}

// ---------------------------------------------------------------------------
// Aggregation: one wave per destination node. lane holds C/64 channels.
// out = di * ( di*h[i] + sum_e dinv[src]*h[src] ) + bias  [; relu]
// ---------------------------------------------------------------------------
template <int C, bool RELU, typename OutT>
__global__ __launch_bounds__(256) void k_agg(const _Float16* __restrict__ h,
                                             const int* __restrict__ esrc,
                                             const int* __restrict__ off,
                                             const float* __restrict__ dinv,
                                             const float* __restrict__ bias,
                                             OutT* __restrict__ out, int n) {
  constexpr int V = C / 64;
  typedef typename vec_t<V>::fv FV;
  typedef typename vec_t<V>::hv HV;
  int gwave = (blockIdx.x * 256 + threadIdx.x) >> 6;
  int lane = threadIdx.x & 63;
  if (gwave >= n) return;
  const int i = gwave;
  const float di = dinv[i];

  FV acc = di * __builtin_convertvector(
                    *(const HV*)(h + (size_t)i * C + lane * V), FV);

  int e = off[i];
  const int e1 = off[i + 1];
  for (; e + 3 < e1; e += 4) {
    int s0 = esrc[e], s1 = esrc[e + 1], s2 = esrc[e + 2], s3 = esrc[e + 3];
    float w0 = dinv[s0], w1 = dinv[s1], w2 = dinv[s2], w3 = dinv[s3];
    HV v0 = *(const HV*)(h + (size_t)s0 * C + lane * V);
    HV v1 = *(const HV*)(h + (size_t)s1 * C + lane * V);
    HV v2 = *(const HV*)(h + (size_t)s2 * C + lane * V);
    HV v3 = *(const HV*)(h + (size_t)s3 * C + lane * V);
    acc += w0 * __builtin_convertvector(v0, FV);
    acc += w1 * __builtin_convertvector(v1, FV);
    acc += w2 * __builtin_convertvector(v2, FV);
    acc += w3 * __builtin_convertvector(v3, FV);
  }
  for (; e < e1; ++e) {
    int s = esrc[e];
    acc += dinv[s] * __builtin_convertvector(
                         *(const HV*)(h + (size_t)s * C + lane * V), FV);
  }

  FV bv = *(const FV*)(bias + lane * V);
  FV r = acc * di + bv;
  if (RELU) {
#pragma unroll
    for (int v = 0; v < V; ++v) r[v] = fmaxf(r[v], 0.f);
  }
  if constexpr (sizeof(OutT) == 2) {
    *(HV*)(out + (size_t)i * C + lane * V) = __builtin_convertvector(r, HV);
  } else {
    *(FV*)(out + (size_t)i * C + lane * V) = r;
  }
}

// ---------------------------------------------------------------------------
extern "C" void kernel_launch(void* const* d_in, const int* in_sizes, int n_in,
                              void* d_out, int out_size, void* d_ws, size_t ws_size,
                              hipStream_t stream) {
  const float* x  = (const float*)d_in[0];
  const int*   ei = (const int*)d_in[1];
  const float* W1 = (const float*)d_in[2];
  const float* b1 = (const float*)d_in[3];
  const float* W2 = (const float*)d_in[4];
  const float* b2 = (const float*)d_in[5];
  float* out = (float*)d_out;

  const int IN_CH = 256, HID = 256, OUT = 128;
  const int N = in_sizes[0] / IN_CH;   // 100000
  const int E = in_sizes[1] / 2;       // 3200000
  const int* src = ei;
  const int* dst = ei + E;
  const int NB = (N + NPB - 1) / NPB;  // 391 buckets

  // workspace layout
  char* p = (char*)d_ws;
  auto alloc = [&](size_t bytes) {
    void* r = (void*)p;
    p += (bytes + 255) & ~(size_t)255;
    return r;
  };
  _Float16* h1   = (_Float16*)alloc((size_t)N * HID * 2);  // reused as h2
  _Float16* h1r  = (_Float16*)alloc((size_t)N * HID * 2);
  int*      esrc = (int*)alloc((size_t)E * 4);
  uint2*    tmp  = (uint2*)alloc((size_t)E * 8);
  int*      off  = (int*)alloc((size_t)(N + 1) * 4);
  float*    dinv = (float*)alloc((size_t)N * 4);
  int*      bcnt = (int*)alloc((size_t)(NB + 1) * 4);
  int*      bbase= (int*)alloc((size_t)(NB + 1) * 4);
  int*      gcur = (int*)alloc((size_t)(NB + 1) * 4);
  _Float16* w1h  = (_Float16*)alloc((size_t)IN_CH * HID * 2);
  _Float16* w1l  = (_Float16*)alloc((size_t)IN_CH * HID * 2);
  _Float16* w2h  = (_Float16*)alloc((size_t)HID * OUT * 2);
  _Float16* w2l  = (_Float16*)alloc((size_t)HID * OUT * 2);
  if ((size_t)(p - (char*)d_ws) > ws_size) {
    fprintf(stderr, "kernel_launch: ws too small (need %zu, have %zu)\n",
            (size_t)(p - (char*)d_ws), ws_size);
    return;
  }

  const int nBlkP = (E + PCHUNK - 1) / PCHUNK;  // 391

  // 1-2. bucket histogram + scan
  k_zero<<<(NB + 255) / 256, 256, 0, stream>>>(bcnt, NB);
  k_bhist<<<nBlkP, 256, 0, stream>>>(dst, bcnt, E, NB);
  k_bscan<<<1, 512, 0, stream>>>(bcnt, bbase, gcur, NB);
  // 3. partition into buckets
  k_partition<<<nBlkP, 256, 0, stream>>>(src, dst, gcur, tmp, E, NB);
  // 4. per-bucket sort -> esrc, off, dinv
  k_bucket<<<NB, 256, 0, stream>>>(tmp, bbase, off, dinv, esrc, N);
  // 5. W splits (transposed)
  k_castWT<<<(IN_CH * HID + 255) / 256, 256, 0, stream>>>(W1, w1h, w1l, IN_CH, HID);
  k_castWT<<<(HID * OUT + 255) / 256, 256, 0, stream>>>(W2, w2h, w2l, HID, OUT);
  // 6. h1 = fp16(x @ W1)  (split-fp16 MFMA, 3 terms)
  dim3 g1((N + 127) / 128, HID / 128);
  k_gemm_mfma<float, 3><<<g1, 256, 0, stream>>>(x, w1h, w1l, h1, N, HID, IN_CH);
  // 7. agg layer 1 (+bias, relu) -> h1r fp16
  int aggBlk = (N + 3) / 4;  // 4 waves per block, wave per node
  k_agg<256, true, _Float16><<<aggBlk, 256, 0, stream>>>(h1, esrc, off, dinv, b1, h1r, N);
  // 8. h2 = fp16(h1r @ W2)  (2 terms; writes into h1 buffer)
  dim3 g2((N + 127) / 128, OUT / 128);
  k_gemm_mfma<_Float16, 2><<<g2, 256, 0, stream>>>(h1r, w2h, w2l, h1, N, OUT, HID);
  // 9. agg layer 2 (+bias) -> out fp32
  k_agg<128, false, float><<<aggBlk, 256, 0, stream>>>(h1, esrc, off, dinv, b2, out, N);
}